// Round 7
// baseline (306.242 us; speedup 1.0000x reference)
//
#include <hip/hip_runtime.h>
#include <hip/hip_bf16.h>
#include <math.h>

// Problem constants (fixed by setup_inputs)
#define B_ 16
#define L_ 1024
#define E_ 512
#define H_ 8
#define DH 64

typedef unsigned short u16;
typedef __attribute__((ext_vector_type(8))) short bf16x8;
typedef __attribute__((ext_vector_type(8))) unsigned short u16x8;
typedef __attribute__((ext_vector_type(4))) float f32x4;

#define MFMA16(A, B, C) __builtin_amdgcn_mfma_f32_16x16x32_bf16(A, B, C, 0, 0, 0)

__device__ inline u16 f2b(float x) {
    __hip_bfloat16 h = __float2bfloat16(x);
    u16 u; __builtin_memcpy(&u, &h, 2); return u;
}

// ---------------- QueryScaler precompute ----------------
// Folds: R_softplus0 * softplus(s) * (1/sqrt(Dh)) * log2(e)  -> exp2 softmax
__global__ void qscale_kernel(const float* __restrict__ qs_scale,
                              float* __restrict__ qscale) {
    int d = threadIdx.x;
    if (d < DH) {
        float x = qs_scale[d];
        float sp = (x > 20.f) ? x : log1pf(expf(x));
        qscale[d] = 1.442695041f * sp * 0.125f * 1.442695041f;
    }
}

// ---------------- fp32 -> bf16 conversion (x, w_in, w_out) ----------------
__global__ __launch_bounds__(256) void cvt_bf16(
    const float* __restrict__ x, const float* __restrict__ wi,
    const float* __restrict__ wo, u16* __restrict__ xb,
    u16* __restrict__ wib, u16* __restrict__ wob)
{
    int i = blockIdx.x * 256 + threadIdx.x;
    const float* src; u16* dst; size_t off;
    if (i < 1048576)      { src = x;  dst = xb;  off = (size_t)i * 8; }
    else if (i < 1146880) { src = wi; dst = wib; off = (size_t)(i - 1048576) * 8; }
    else                  { src = wo; dst = wob; off = (size_t)(i - 1146880) * 8; }
    float4 a = *(const float4*)(src + off);
    float4 b = *(const float4*)(src + off + 4);
    u16x8 r;
    r[0] = f2b(a.x); r[1] = f2b(a.y); r[2] = f2b(a.z); r[3] = f2b(a.w);
    r[4] = f2b(b.x); r[5] = f2b(b.y); r[6] = f2b(b.z); r[7] = f2b(b.w);
    *(u16x8*)(dst + off) = r;
}

// ---------------- bf16 MFMA GEMM: C = A(M,512) @ W(N,512)^T + bias --------
// 128x128 tile, BK=32, 4 waves (2x2), each wave 4x4 16x16x32 fragments.
template<int MODE>
__global__ __launch_bounds__(256) void gemm_bf16(
    const u16* __restrict__ A, const u16* __restrict__ W,
    const float* __restrict__ bias, const float* __restrict__ qscale,
    float* __restrict__ Dout, u16* __restrict__ Qb, u16* __restrict__ Kb,
    u16* __restrict__ Vtb)
{
    __shared__ u16 sA[128][36];
    __shared__ u16 sB[128][36];
    const int tid = threadIdx.x;
    const int m0 = blockIdx.x * 128;
    const int n0 = blockIdx.y * 128;
    const int wid = tid >> 6, lane = tid & 63;
    const int g = lane >> 4, c = lane & 15;
    const int wr = wid >> 1, wc = wid & 1;

    const int srow = tid >> 2;
    const int sslot = tid & 3;
    const u16* Ap = A + (size_t)(m0 + srow) * 512 + sslot * 8;
    const u16* Wp = W + (size_t)(n0 + srow) * 512 + sslot * 8;

    f32x4 acc[4][4];
    #pragma unroll
    for (int m = 0; m < 4; m++)
        #pragma unroll
        for (int n = 0; n < 4; n++) acc[m][n] = (f32x4){0.f, 0.f, 0.f, 0.f};

    bf16x8 ra0 = *(const bf16x8*)(Ap);
    bf16x8 ra1 = *(const bf16x8*)(Ap + (size_t)64 * 512);
    bf16x8 rb0 = *(const bf16x8*)(Wp);
    bf16x8 rb1 = *(const bf16x8*)(Wp + (size_t)64 * 512);

    #pragma unroll 1
    for (int ks = 0; ks < 16; ks++) {
        __syncthreads();
        *(bf16x8*)&sA[srow][sslot * 8] = ra0;
        *(bf16x8*)&sA[srow + 64][sslot * 8] = ra1;
        *(bf16x8*)&sB[srow][sslot * 8] = rb0;
        *(bf16x8*)&sB[srow + 64][sslot * 8] = rb1;
        __syncthreads();
        if (ks < 15) {
            int k0 = (ks + 1) * 32;
            ra0 = *(const bf16x8*)(Ap + k0);
            ra1 = *(const bf16x8*)(Ap + (size_t)64 * 512 + k0);
            rb0 = *(const bf16x8*)(Wp + k0);
            rb1 = *(const bf16x8*)(Wp + (size_t)64 * 512 + k0);
        }
        bf16x8 af[4], bfr[4];
        #pragma unroll
        for (int m = 0; m < 4; m++)
            af[m] = *(const bf16x8*)&sA[wr * 64 + m * 16 + c][g * 8];
        #pragma unroll
        for (int n = 0; n < 4; n++)
            bfr[n] = *(const bf16x8*)&sB[wc * 64 + n * 16 + c][g * 8];
        #pragma unroll
        for (int m = 0; m < 4; m++)
            #pragma unroll
            for (int n = 0; n < 4; n++)
                acc[m][n] = MFMA16(af[m], bfr[n], acc[m][n]);
    }

    #pragma unroll
    for (int m = 0; m < 4; m++) {
        int rbase = m0 + wr * 64 + m * 16 + 4 * g;
        #pragma unroll
        for (int n = 0; n < 4; n++) {
            int f = n0 + wc * 64 + n * 16 + c;
            f32x4 v = acc[m][n];
            float bv = bias[f];
            if (MODE == 1) {
                #pragma unroll
                for (int reg = 0; reg < 4; reg++)
                    Dout[(size_t)(rbase + reg) * E_ + f] = v[reg] + bv;
            } else {
                int part = f >> 9, w = f & 511, h = w >> 6, d = w & 63;
                int bb = rbase >> 10;
                int l0 = rbase & 1023;
                size_t bh = (size_t)(bb * H_ + h);
                if (part == 0) {
                    float qs = qscale[d];
                    #pragma unroll
                    for (int reg = 0; reg < 4; reg++)
                        Qb[(bh * L_ + l0 + reg) * DH + d] = f2b((v[reg] + bv) * qs);
                } else if (part == 1) {
                    #pragma unroll
                    for (int reg = 0; reg < 4; reg++)
                        Kb[(bh * L_ + l0 + reg) * DH + d] = f2b(v[reg] + bv);
                } else {
                    ushort4 pk;
                    pk.x = f2b(v[0] + bv); pk.y = f2b(v[1] + bv);
                    pk.z = f2b(v[2] + bv); pk.w = f2b(v[3] + bv);
                    *(ushort4*)(Vtb + (bh * DH + d) * L_ + l0) = pk;
                }
            }
        }
    }
}

// ---------------- MFMA flash attention ----------------
// 4 waves/block, each wave = one (bh, 16-row Q tile), fully independent
// (per-wave LDS region, NO __syncthreads). Swapped QK^T; softmax state is
// column-space (q = lane&15), PV accumulator is row-space (q = 4g+reg) ->
// rescale remaps corr via __shfl(corr, 4g+r). Register-double-buffered K/V
// (prefetch kt+32 while computing kt). Scores arrive pre-scaled by log2(e)
// (folded into qscale) -> exp2f softmax. Defer-max: skip rescale while the
// tile max is within 8 (log2 domain) of the running max.
__global__ __launch_bounds__(256, 4) void attn_mfma(
    const u16* __restrict__ Q, const u16* __restrict__ K,
    const u16* __restrict__ Vt, const unsigned char* __restrict__ mask,
    u16* __restrict__ O)
{
    __shared__ u16 P_lds[4][16][36];           // per-wave, 72B pitch (conflict-free)

    const int bid = blockIdx.x;                // 0..2047
    const int w = (bid & 7) * 256 + (bid >> 3);  // XCD-bijective swizzle
    const int bh = w >> 4;                     // 0..127
    const int wid = threadIdx.x >> 6;
    const int qt = (w & 15) * 4 + wid;         // 0..63
    const int b = bh >> 3;
    const int h = bh & (H_ - 1);

    const int lane = threadIdx.x & 63;
    const int g = lane >> 4;
    const int c = lane & 15;

    const u16* Qp = Q + ((size_t)bh * L_ + qt * 16) * DH;
    const u16* Kp = K + (size_t)bh * L_ * DH;
    const u16* Vp = Vt + (size_t)bh * DH * L_;
    const unsigned char* mp = mask + (size_t)b * L_;

    // whole-row mask presence check (hoisted; mask is usually all-false)
    unsigned int mor = 0;
    {
        const unsigned int* mp32 = (const unsigned int*)mp;
        #pragma unroll
        for (int i = 0; i < 4; i++) mor |= mp32[lane + i * 64];
    }
    const bool anyMask = (__ballot(mor != 0) != 0ULL);

    bf16x8 qf0 = *(const bf16x8*)(Qp + c * DH + g * 8);
    bf16x8 qf1 = *(const bf16x8*)(Qp + c * DH + 32 + g * 8);

    f32x4 oacc[4];
    #pragma unroll
    for (int i = 0; i < 4; i++) oacc[i] = (f32x4){0.f, 0.f, 0.f, 0.f};
    float mrun = -INFINITY, lrun = 0.f;

    // per-wave K/V fragment loaders (32-key tile at key offset kt)
    auto loadK = [&](bf16x8* KF, int kt) {
        const u16* kp0 = Kp + (size_t)(kt + c) * DH + g * 8;
        KF[0] = *(const bf16x8*)(kp0);
        KF[1] = *(const bf16x8*)(kp0 + 32);
        KF[2] = *(const bf16x8*)(kp0 + 16 * DH);
        KF[3] = *(const bf16x8*)(kp0 + 16 * DH + 32);
    };
    auto loadV = [&](bf16x8* VF, int kt) {
        #pragma unroll
        for (int dc = 0; dc < 4; dc++)
            VF[dc] = *(const bf16x8*)(Vp + (size_t)(dc * 16 + c) * L_ + kt + g * 8);
    };

    auto body = [&](bf16x8* KF, bf16x8* VF, int kt) {
        f32x4 st0 = {0.f, 0.f, 0.f, 0.f}, st1 = {0.f, 0.f, 0.f, 0.f};
        st0 = MFMA16(KF[0], qf0, st0);
        st0 = MFMA16(KF[1], qf1, st0);
        st1 = MFMA16(KF[2], qf0, st1);
        st1 = MFMA16(KF[3], qf1, st1);
        // lane: S^T[key = kt+4g+r (st0) / kt+16+4g+r (st1)][q = q0+c]

        if (anyMask) {
            #pragma unroll
            for (int r = 0; r < 4; r++) {
                if (mp[kt + 4 * g + r])      st0[r] = -1e9f;
                if (mp[kt + 16 + 4 * g + r]) st1[r] = -1e9f;
            }
        }

        float tm = fmaxf(fmaxf(fmaxf(st0[0], st0[1]), fmaxf(st0[2], st0[3])),
                         fmaxf(fmaxf(st1[0], st1[1]), fmaxf(st1[2], st1[3])));
        tm = fmaxf(tm, __shfl_xor(tm, 16));
        tm = fmaxf(tm, __shfl_xor(tm, 32));

        if (!__all(tm <= mrun + 8.f)) {        // wave-uniform rescale (defer-max)
            float mnew = fmaxf(mrun, tm);
            float corr = exp2f(mrun - mnew);   // corr for q = c (column space)
            lrun *= corr;
            float cr[4];
            #pragma unroll
            for (int r = 0; r < 4; r++) cr[r] = __shfl(corr, 4 * g + r);
            #pragma unroll
            for (int dc = 0; dc < 4; dc++) {
                #pragma unroll
                for (int r = 0; r < 4; r++) oacc[dc][r] *= cr[r];
            }
            mrun = mnew;
        }

        float p0[4], p1[4], ls = 0.f;
        #pragma unroll
        for (int r = 0; r < 4; r++) {
            p0[r] = exp2f(st0[r] - mrun);
            p1[r] = exp2f(st1[r] - mrun);
            ls += p0[r] + p1[r];
        }
        ls += __shfl_xor(ls, 16);
        ls += __shfl_xor(ls, 32);
        lrun += ls;

        // P^T -> per-wave LDS [q][key] (bf16), re-read as PV A-fragment.
        // Same-wave DS ops are in-order; fences keep the compiler honest.
        ushort4 pk0, pk1;
        pk0.x = f2b(p0[0]); pk0.y = f2b(p0[1]); pk0.z = f2b(p0[2]); pk0.w = f2b(p0[3]);
        pk1.x = f2b(p1[0]); pk1.y = f2b(p1[1]); pk1.z = f2b(p1[2]); pk1.w = f2b(p1[3]);
        *(ushort4*)(&P_lds[wid][c][4 * g]) = pk0;
        *(ushort4*)(&P_lds[wid][c][16 + 4 * g]) = pk1;
        asm volatile("s_waitcnt lgkmcnt(0)" ::: "memory");
        __builtin_amdgcn_sched_barrier(0);
        bf16x8 pf = *(const bf16x8*)(&P_lds[wid][c][g * 8]);
        asm volatile("" ::: "memory");

        #pragma unroll
        for (int dc = 0; dc < 4; dc++)
            oacc[dc] = MFMA16(pf, VF[dc], oacc[dc]);
    };

    bf16x8 kA[4], vA[4], kB[4], vB[4];
    loadK(kA, 0); loadV(vA, 0);
    #pragma unroll 1
    for (int kt = 0; kt < L_; kt += 64) {
        loadK(kB, kt + 32); loadV(vB, kt + 32);
        body(kA, vA, kt);
        // last prefetch reads 4KB past K/V end: still inside workspace, unused
        loadK(kA, kt + 64); loadV(vA, kt + 64);
        body(kB, vB, kt + 32);
    }

    float linv[4];
    #pragma unroll
    for (int r = 0; r < 4; r++) {
        float lq = __shfl(lrun, 4 * g + r);
        linv[r] = 1.f / lq;
    }
    #pragma unroll
    for (int dc = 0; dc < 4; dc++) {
        #pragma unroll
        for (int r = 0; r < 4; r++) {
            int qrow = qt * 16 + 4 * g + r;
            O[((size_t)(b * L_ + qrow)) * E_ + h * DH + dc * 16 + c] =
                f2b(oacc[dc][r] * linv[r]);
        }
    }
}

// ---------------- host launch ----------------
extern "C" void kernel_launch(void* const* d_in, const int* in_sizes, int n_in,
                              void* d_out, int out_size, void* d_ws, size_t ws_size,
                              hipStream_t stream) {
    const float* x     = (const float*)d_in[0];
    const float* w_in  = (const float*)d_in[1];
    const float* b_in  = (const float*)d_in[2];
    const float* w_out = (const float*)d_in[3];
    const float* b_out = (const float*)d_in[4];
    const float* qs    = (const float*)d_in[5];
    const unsigned char* mask = (const unsigned char*)d_in[6];
    float* out = (float*)d_out;

    char* base = (char*)d_ws;
    const size_t NELEM = (size_t)B_ * L_ * E_;   // 8388608
    float* qscale = (float*)base;                // 256 B
    u16* xb  = (u16*)(base + 256);
    u16* wib = xb + NELEM;                       // 786432
    u16* wob = wib + 786432;                     // 262144
    u16* Qb  = wob + 262144;
    u16* Kb  = Qb + NELEM;
    u16* Vtb = Kb + NELEM;
    u16* Ob  = Vtb + NELEM;

    qscale_kernel<<<1, 64, 0, stream>>>(qs, qscale);
    cvt_bf16<<<4608, 256, 0, stream>>>(x, w_in, w_out, xb, wib, wob);
    gemm_bf16<0><<<dim3(128, 12), 256, 0, stream>>>(
        xb, wib, b_in, qscale, nullptr, Qb, Kb, Vtb);
    attn_mfma<<<dim3(2048), 256, 0, stream>>>(Qb, Kb, Vtb, mask, Ob);
    gemm_bf16<1><<<dim3(128, 4), 256, 0, stream>>>(
        Ob, wob, b_out, nullptr, out, nullptr, nullptr, nullptr);
}

// Round 10
// 151.950 us; speedup vs baseline: 2.0154x; 2.0154x over previous
//
#include <hip/hip_runtime.h>
#include <hip/hip_bf16.h>
#include <math.h>

// Problem constants (fixed by setup_inputs)
#define B_ 16
#define L_ 1024
#define E_ 512
#define H_ 8
#define DH 64

typedef unsigned short u16;
typedef __attribute__((ext_vector_type(8))) short bf16x8;
typedef __attribute__((ext_vector_type(8))) unsigned short u16x8;
typedef __attribute__((ext_vector_type(4))) float f32x4;

#define MFMA16(A, B, C) __builtin_amdgcn_mfma_f32_16x16x32_bf16(A, B, C, 0, 0, 0)

__device__ inline u16 f2b(float x) {
    __hip_bfloat16 h = __float2bfloat16(x);
    u16 u; __builtin_memcpy(&u, &h, 2); return u;
}

// ---------------- QueryScaler precompute ----------------
// Folds: R_softplus0 * softplus(s) * (1/sqrt(Dh)) * log2(e)  -> exp2 softmax
__global__ void qscale_kernel(const float* __restrict__ qs_scale,
                              float* __restrict__ qscale) {
    int d = threadIdx.x;
    if (d < DH) {
        float x = qs_scale[d];
        float sp = (x > 20.f) ? x : log1pf(expf(x));
        qscale[d] = 1.442695041f * sp * 0.125f * 1.442695041f;
    }
}

// ---------------- fp32 -> bf16 conversion (x, w_in, w_out) ----------------
__global__ __launch_bounds__(256) void cvt_bf16(
    const float* __restrict__ x, const float* __restrict__ wi,
    const float* __restrict__ wo, u16* __restrict__ xb,
    u16* __restrict__ wib, u16* __restrict__ wob)
{
    int i = blockIdx.x * 256 + threadIdx.x;
    const float* src; u16* dst; size_t off;
    if (i < 1048576)      { src = x;  dst = xb;  off = (size_t)i * 8; }
    else if (i < 1146880) { src = wi; dst = wib; off = (size_t)(i - 1048576) * 8; }
    else                  { src = wo; dst = wob; off = (size_t)(i - 1146880) * 8; }
    float4 a = *(const float4*)(src + off);
    float4 b = *(const float4*)(src + off + 4);
    u16x8 r;
    r[0] = f2b(a.x); r[1] = f2b(a.y); r[2] = f2b(a.z); r[3] = f2b(a.w);
    r[4] = f2b(b.x); r[5] = f2b(b.y); r[6] = f2b(b.z); r[7] = f2b(b.w);
    *(u16x8*)(dst + off) = r;
}

// ---------------- bf16 MFMA GEMM: C = A(M,512) @ W(N,512)^T + bias --------
// 128x128 tile, BK=32, 4 waves (2x2), each wave 4x4 16x16x32 fragments.
template<int MODE>
__global__ __launch_bounds__(256) void gemm_bf16(
    const u16* __restrict__ A, const u16* __restrict__ W,
    const float* __restrict__ bias, const float* __restrict__ qscale,
    float* __restrict__ Dout, u16* __restrict__ Qb, u16* __restrict__ Kb,
    u16* __restrict__ Vtb)
{
    __shared__ u16 sA[128][36];
    __shared__ u16 sB[128][36];
    const int tid = threadIdx.x;
    const int m0 = blockIdx.x * 128;
    const int n0 = blockIdx.y * 128;
    const int wid = tid >> 6, lane = tid & 63;
    const int g = lane >> 4, c = lane & 15;
    const int wr = wid >> 1, wc = wid & 1;

    const int srow = tid >> 2;
    const int sslot = tid & 3;
    const u16* Ap = A + (size_t)(m0 + srow) * 512 + sslot * 8;
    const u16* Wp = W + (size_t)(n0 + srow) * 512 + sslot * 8;

    f32x4 acc[4][4];
    #pragma unroll
    for (int m = 0; m < 4; m++)
        #pragma unroll
        for (int n = 0; n < 4; n++) acc[m][n] = (f32x4){0.f, 0.f, 0.f, 0.f};

    bf16x8 ra0 = *(const bf16x8*)(Ap);
    bf16x8 ra1 = *(const bf16x8*)(Ap + (size_t)64 * 512);
    bf16x8 rb0 = *(const bf16x8*)(Wp);
    bf16x8 rb1 = *(const bf16x8*)(Wp + (size_t)64 * 512);

    #pragma unroll 1
    for (int ks = 0; ks < 16; ks++) {
        __syncthreads();
        *(bf16x8*)&sA[srow][sslot * 8] = ra0;
        *(bf16x8*)&sA[srow + 64][sslot * 8] = ra1;
        *(bf16x8*)&sB[srow][sslot * 8] = rb0;
        *(bf16x8*)&sB[srow + 64][sslot * 8] = rb1;
        __syncthreads();
        if (ks < 15) {
            int k0 = (ks + 1) * 32;
            ra0 = *(const bf16x8*)(Ap + k0);
            ra1 = *(const bf16x8*)(Ap + (size_t)64 * 512 + k0);
            rb0 = *(const bf16x8*)(Wp + k0);
            rb1 = *(const bf16x8*)(Wp + (size_t)64 * 512 + k0);
        }
        bf16x8 af[4], bfr[4];
        #pragma unroll
        for (int m = 0; m < 4; m++)
            af[m] = *(const bf16x8*)&sA[wr * 64 + m * 16 + c][g * 8];
        #pragma unroll
        for (int n = 0; n < 4; n++)
            bfr[n] = *(const bf16x8*)&sB[wc * 64 + n * 16 + c][g * 8];
        #pragma unroll
        for (int m = 0; m < 4; m++)
            #pragma unroll
            for (int n = 0; n < 4; n++)
                acc[m][n] = MFMA16(af[m], bfr[n], acc[m][n]);
    }

    #pragma unroll
    for (int m = 0; m < 4; m++) {
        int rbase = m0 + wr * 64 + m * 16 + 4 * g;
        #pragma unroll
        for (int n = 0; n < 4; n++) {
            int f = n0 + wc * 64 + n * 16 + c;
            f32x4 v = acc[m][n];
            float bv = bias[f];
            if (MODE == 1) {
                #pragma unroll
                for (int reg = 0; reg < 4; reg++)
                    Dout[(size_t)(rbase + reg) * E_ + f] = v[reg] + bv;
            } else {
                int part = f >> 9, w = f & 511, h = w >> 6, d = w & 63;
                int bb = rbase >> 10;
                int l0 = rbase & 1023;
                size_t bh = (size_t)(bb * H_ + h);
                if (part == 0) {
                    float qs = qscale[d];
                    #pragma unroll
                    for (int reg = 0; reg < 4; reg++)
                        Qb[(bh * L_ + l0 + reg) * DH + d] = f2b((v[reg] + bv) * qs);
                } else if (part == 1) {
                    #pragma unroll
                    for (int reg = 0; reg < 4; reg++)
                        Kb[(bh * L_ + l0 + reg) * DH + d] = f2b(v[reg] + bv);
                } else {
                    ushort4 pk;
                    pk.x = f2b(v[0] + bv); pk.y = f2b(v[1] + bv);
                    pk.z = f2b(v[2] + bv); pk.w = f2b(v[3] + bv);
                    *(ushort4*)(Vtb + (bh * DH + d) * L_ + l0) = pk;
                }
            }
        }
    }
}

// ---------------- MFMA flash attention (block-cooperative LDS staging) ----
// Block = 4 waves, SAME bh, 4 consecutive 16-row Q tiles. Per 32-key step the
// block stages K-tile (4KB) + V^T-tile (4KB) into double-buffered LDS via
// global_load_lds(16B). RACE FIX (round 9): each wave EXPLICITLY drains its
// own DMA (s_waitcnt vmcnt(0)) before signaling the barrier — do not rely on
// __syncthreads to emit the vmcnt drain. After the barrier, all 4 quarters
// have provably landed.
// Swizzle (rule 21): LDS dest linear, global SOURCE carries the inverse XOR,
// reads apply the same XOR. K slot = row*8+(ch^(row&7));
// V slot = row*4+(ch^(row&3)^((row>>2)&3)). Reads uniform 8-per-bank.
// Softmax identical to verified round-4/7 body.
__global__ __launch_bounds__(256, 4) void attn_mfma(
    const u16* __restrict__ Q, const u16* __restrict__ K,
    const u16* __restrict__ Vt, const unsigned char* __restrict__ mask,
    u16* __restrict__ O)
{
    __shared__ u16 Kbuf[2][2048];              // 2 x 4KB (256 slots x 16B)
    __shared__ u16 Vbuf[2][2048];              // 2 x 4KB
    __shared__ u16 P_lds[4][16][36];           // per-wave, 72B pitch

    const int bid = blockIdx.x;                // 0..2047
    const int w = (bid & 7) * 256 + (bid >> 3);  // XCD-bijective swizzle
    const int bh = w >> 4;                     // 0..127 (one bh = 16 blocks, 1 XCD)
    const int tid = threadIdx.x;
    const int wid = tid >> 6;
    const int qt = (w & 15) * 4 + wid;         // 0..63
    const int b = bh >> 3;
    const int h = bh & (H_ - 1);

    const int lane = tid & 63;
    const int g = lane >> 4;
    const int c = lane & 15;

    const u16* Qp = Q + ((size_t)bh * L_ + qt * 16) * DH;
    const u16* Kp = K + (size_t)bh * L_ * DH;
    const u16* Vp = Vt + (size_t)bh * DH * L_;
    const unsigned char* mp = mask + (size_t)b * L_;

    // staging map: thread covers slot tid; inverse-swizzled global chunk
    const int krow = tid >> 3, kch = (tid & 7) ^ (krow & 7);
    const int vrow = tid >> 2, vch = (tid & 3) ^ ((vrow & 3) ^ ((vrow >> 2) & 3));
    const u16* Kg = Kp + (size_t)krow * DH + kch * 8;   // + kt*DH per tile
    const u16* Vg = Vp + (size_t)vrow * L_ + vch * 8;   // + kt per tile

    auto stage = [&](int nbuf, int kt) {
        __builtin_amdgcn_global_load_lds(
            (const __attribute__((address_space(1))) unsigned int*)(Kg + (size_t)kt * DH),
            (__attribute__((address_space(3))) unsigned int*)&Kbuf[nbuf][wid * 512],
            16, 0, 0);
        __builtin_amdgcn_global_load_lds(
            (const __attribute__((address_space(1))) unsigned int*)(Vg + kt),
            (__attribute__((address_space(3))) unsigned int*)&Vbuf[nbuf][wid * 512],
            16, 0, 0);
    };

    // whole-row mask presence check (hoisted; mask is usually all-false)
    unsigned int mor = 0;
    {
        const unsigned int* mp32 = (const unsigned int*)mp;
        #pragma unroll
        for (int i = 0; i < 4; i++) mor |= mp32[lane + i * 64];
    }
    const bool anyMask = (__ballot(mor != 0) != 0ULL);

    stage(0, 0);                               // prefetch tile 0

    bf16x8 qf0 = *(const bf16x8*)(Qp + c * DH + g * 8);
    bf16x8 qf1 = *(const bf16x8*)(Qp + c * DH + 32 + g * 8);

    f32x4 oacc[4];
    #pragma unroll
    for (int i = 0; i < 4; i++) oacc[i] = (f32x4){0.f, 0.f, 0.f, 0.f};
    float mrun = -INFINITY, lrun = 0.f;

    // read-side swizzled slot offsets (u16 indices; slot*8)
    const int ks0 = (c * 8 + (g ^ (c & 7))) * 8;
    const int ks1 = (c * 8 + ((g + 4) ^ (c & 7))) * 8;
    const int swzv = (c & 3) ^ ((c >> 2) & 3);

    #pragma unroll 1
    for (int t = 0; t < 32; ++t) {
        const int cur = t & 1;
        const int kt = t * 32;
        // RACE FIX: retire this wave's own staging DMA before the barrier.
        asm volatile("s_waitcnt vmcnt(0) lgkmcnt(0)" ::: "memory");
        __syncthreads();

        bf16x8 k00 = *(const bf16x8*)&Kbuf[cur][ks0];
        bf16x8 k01 = *(const bf16x8*)&Kbuf[cur][ks1];
        bf16x8 k10 = *(const bf16x8*)&Kbuf[cur][ks0 + 1024];   // rows c+16
        bf16x8 k11 = *(const bf16x8*)&Kbuf[cur][ks1 + 1024];
        bf16x8 vb[4];
        #pragma unroll
        for (int dc = 0; dc < 4; dc++)
            vb[dc] = *(const bf16x8*)&Vbuf[cur][((dc * 16 + c) * 4 + (g ^ swzv)) * 8];

        if (t < 31) stage(cur ^ 1, kt + 32);   // prefetch next tile (other buffer)

        f32x4 st0 = {0.f, 0.f, 0.f, 0.f}, st1 = {0.f, 0.f, 0.f, 0.f};
        st0 = MFMA16(k00, qf0, st0);
        st0 = MFMA16(k01, qf1, st0);
        st1 = MFMA16(k10, qf0, st1);
        st1 = MFMA16(k11, qf1, st1);
        // lane: S^T[key = kt+4g+r (st0) / kt+16+4g+r (st1)][q = q0+c]

        if (anyMask) {
            #pragma unroll
            for (int r = 0; r < 4; r++) {
                if (mp[kt + 4 * g + r])      st0[r] = -1e9f;
                if (mp[kt + 16 + 4 * g + r]) st1[r] = -1e9f;
            }
        }

        float tm = fmaxf(fmaxf(fmaxf(st0[0], st0[1]), fmaxf(st0[2], st0[3])),
                         fmaxf(fmaxf(st1[0], st1[1]), fmaxf(st1[2], st1[3])));
        tm = fmaxf(tm, __shfl_xor(tm, 16));
        tm = fmaxf(tm, __shfl_xor(tm, 32));

        if (!__all(tm <= mrun + 8.f)) {        // wave-uniform rescale (defer-max)
            float mnew = fmaxf(mrun, tm);
            float corr = exp2f(mrun - mnew);   // corr for q = c (column space)
            lrun *= corr;
            float cr[4];
            #pragma unroll
            for (int r = 0; r < 4; r++) cr[r] = __shfl(corr, 4 * g + r);
            #pragma unroll
            for (int dc = 0; dc < 4; dc++) {
                #pragma unroll
                for (int r = 0; r < 4; r++) oacc[dc][r] *= cr[r];
            }
            mrun = mnew;
        }

        float p0[4], p1[4], ls = 0.f;
        #pragma unroll
        for (int r = 0; r < 4; r++) {
            p0[r] = exp2f(st0[r] - mrun);
            p1[r] = exp2f(st1[r] - mrun);
            ls += p0[r] + p1[r];
        }
        ls += __shfl_xor(ls, 16);
        ls += __shfl_xor(ls, 32);
        lrun += ls;

        // P^T -> per-wave LDS [q][key] (bf16), re-read as PV A-fragment.
        ushort4 pk0, pk1;
        pk0.x = f2b(p0[0]); pk0.y = f2b(p0[1]); pk0.z = f2b(p0[2]); pk0.w = f2b(p0[3]);
        pk1.x = f2b(p1[0]); pk1.y = f2b(p1[1]); pk1.z = f2b(p1[2]); pk1.w = f2b(p1[3]);
        *(ushort4*)(&P_lds[wid][c][4 * g]) = pk0;
        *(ushort4*)(&P_lds[wid][c][16 + 4 * g]) = pk1;
        asm volatile("s_waitcnt lgkmcnt(0)" ::: "memory");
        __builtin_amdgcn_sched_barrier(0);
        bf16x8 pf = *(const bf16x8*)(&P_lds[wid][c][g * 8]);
        asm volatile("" ::: "memory");

        #pragma unroll
        for (int dc = 0; dc < 4; dc++)
            oacc[dc] = MFMA16(pf, vb[dc], oacc[dc]);
        // oacc[dc]: lane holds O[q = 4g+r][d = dc*16+c]
    }

    float linv[4];
    #pragma unroll
    for (int r = 0; r < 4; r++) {
        float lq = __shfl(lrun, 4 * g + r);
        linv[r] = 1.f / lq;
    }
    #pragma unroll
    for (int dc = 0; dc < 4; dc++) {
        #pragma unroll
        for (int r = 0; r < 4; r++) {
            int qrow = qt * 16 + 4 * g + r;
            O[((size_t)(b * L_ + qrow)) * E_ + h * DH + dc * 16 + c] =
                f2b(oacc[dc][r] * linv[r]);
        }
    }
}

// ---------------- host launch ----------------
extern "C" void kernel_launch(void* const* d_in, const int* in_sizes, int n_in,
                              void* d_out, int out_size, void* d_ws, size_t ws_size,
                              hipStream_t stream) {
    const float* x     = (const float*)d_in[0];
    const float* w_in  = (const float*)d_in[1];
    const float* b_in  = (const float*)d_in[2];
    const float* w_out = (const float*)d_in[3];
    const float* b_out = (const float*)d_in[4];
    const float* qs    = (const float*)d_in[5];
    const unsigned char* mask = (const unsigned char*)d_in[6];
    float* out = (float*)d_out;

    char* base = (char*)d_ws;
    const size_t NELEM = (size_t)B_ * L_ * E_;   // 8388608
    float* qscale = (float*)base;                // 256 B
    u16* xb  = (u16*)(base + 256);
    u16* wib = xb + NELEM;                       // 786432
    u16* wob = wib + 786432;                     // 262144
    u16* Qb  = wob + 262144;
    u16* Kb  = Qb + NELEM;
    u16* Vtb = Kb + NELEM;
    u16* Ob  = Vtb + NELEM;

    qscale_kernel<<<1, 64, 0, stream>>>(qs, qscale);
    cvt_bf16<<<4608, 256, 0, stream>>>(x, w_in, w_out, xb, wib, wob);
    gemm_bf16<0><<<dim3(128, 12), 256, 0, stream>>>(
        xb, wib, b_in, qscale, nullptr, Qb, Kb, Vtb);
    attn_mfma<<<dim3(2048), 256, 0, stream>>>(Qb, Kb, Vtb, mask, Ob);
    gemm_bf16<1><<<dim3(128, 4), 256, 0, stream>>>(
        Ob, wob, b_out, nullptr, out, nullptr, nullptr, nullptr);
}

// Round 11
// 129.994 us; speedup vs baseline: 2.3558x; 1.1689x over previous
//
#include <hip/hip_runtime.h>
#include <hip/hip_bf16.h>
#include <math.h>

// Problem constants (fixed by setup_inputs)
#define B_ 16
#define L_ 1024
#define E_ 512
#define H_ 8
#define DH 64

typedef unsigned short u16;
typedef __attribute__((ext_vector_type(8))) short bf16x8;
typedef __attribute__((ext_vector_type(8))) unsigned short u16x8;
typedef __attribute__((ext_vector_type(4))) float f32x4;
typedef __attribute__((ext_vector_type(16))) float f32x16;

#define MFMA16(A, B, C) __builtin_amdgcn_mfma_f32_16x16x32_bf16(A, B, C, 0, 0, 0)
#define MFMA32(A, B, C) __builtin_amdgcn_mfma_f32_32x32x16_bf16(A, B, C, 0, 0, 0)

#if __has_builtin(__builtin_amdgcn_exp2f)
#define EXP2(x) __builtin_amdgcn_exp2f(x)
#else
#define EXP2(x) exp2f(x)
#endif

__device__ inline u16 f2b(float x) {
    __hip_bfloat16 h = __float2bfloat16(x);
    u16 u; __builtin_memcpy(&u, &h, 2); return u;
}

// hardware packed f32->bf16 (RNE), lo = a, hi = b
__device__ inline unsigned int cvt_pk_bf16(float a, float b) {
    unsigned int r;
    asm("v_cvt_pk_bf16_f32 %0, %1, %2" : "=v"(r) : "v"(a), "v"(b));
    return r;
}

// ---------------- QueryScaler precompute ----------------
// Folds: R_softplus0 * softplus(s) * (1/sqrt(Dh)) * log2(e)  -> exp2 softmax
__global__ void qscale_kernel(const float* __restrict__ qs_scale,
                              float* __restrict__ qscale) {
    int d = threadIdx.x;
    if (d < DH) {
        float x = qs_scale[d];
        float sp = (x > 20.f) ? x : log1pf(expf(x));
        qscale[d] = 1.442695041f * sp * 0.125f * 1.442695041f;
    }
}

// ---------------- fp32 -> bf16 conversion (x, w_in, w_out) ----------------
__global__ __launch_bounds__(256) void cvt_bf16(
    const float* __restrict__ x, const float* __restrict__ wi,
    const float* __restrict__ wo, u16* __restrict__ xb,
    u16* __restrict__ wib, u16* __restrict__ wob)
{
    int i = blockIdx.x * 256 + threadIdx.x;
    const float* src; u16* dst; size_t off;
    if (i < 1048576)      { src = x;  dst = xb;  off = (size_t)i * 8; }
    else if (i < 1146880) { src = wi; dst = wib; off = (size_t)(i - 1048576) * 8; }
    else                  { src = wo; dst = wob; off = (size_t)(i - 1146880) * 8; }
    float4 a = *(const float4*)(src + off);
    float4 b = *(const float4*)(src + off + 4);
    u16x8 r;
    r[0] = f2b(a.x); r[1] = f2b(a.y); r[2] = f2b(a.z); r[3] = f2b(a.w);
    r[4] = f2b(b.x); r[5] = f2b(b.y); r[6] = f2b(b.z); r[7] = f2b(b.w);
    *(u16x8*)(dst + off) = r;
}

// ---------------- bf16 MFMA GEMM: C = A(M,512) @ W(N,512)^T + bias --------
// 128x128 tile, BK=32, 4 waves (2x2), each wave 4x4 16x16x32 fragments.
template<int MODE>
__global__ __launch_bounds__(256) void gemm_bf16(
    const u16* __restrict__ A, const u16* __restrict__ W,
    const float* __restrict__ bias, const float* __restrict__ qscale,
    float* __restrict__ Dout, u16* __restrict__ Qb, u16* __restrict__ Kb,
    u16* __restrict__ Vtb)
{
    __shared__ u16 sA[128][36];
    __shared__ u16 sB[128][36];
    const int tid = threadIdx.x;
    const int m0 = blockIdx.x * 128;
    const int n0 = blockIdx.y * 128;
    const int wid = tid >> 6, lane = tid & 63;
    const int g = lane >> 4, c = lane & 15;
    const int wr = wid >> 1, wc = wid & 1;

    const int srow = tid >> 2;
    const int sslot = tid & 3;
    const u16* Ap = A + (size_t)(m0 + srow) * 512 + sslot * 8;
    const u16* Wp = W + (size_t)(n0 + srow) * 512 + sslot * 8;

    f32x4 acc[4][4];
    #pragma unroll
    for (int m = 0; m < 4; m++)
        #pragma unroll
        for (int n = 0; n < 4; n++) acc[m][n] = (f32x4){0.f, 0.f, 0.f, 0.f};

    bf16x8 ra0 = *(const bf16x8*)(Ap);
    bf16x8 ra1 = *(const bf16x8*)(Ap + (size_t)64 * 512);
    bf16x8 rb0 = *(const bf16x8*)(Wp);
    bf16x8 rb1 = *(const bf16x8*)(Wp + (size_t)64 * 512);

    #pragma unroll 1
    for (int ks = 0; ks < 16; ks++) {
        __syncthreads();
        *(bf16x8*)&sA[srow][sslot * 8] = ra0;
        *(bf16x8*)&sA[srow + 64][sslot * 8] = ra1;
        *(bf16x8*)&sB[srow][sslot * 8] = rb0;
        *(bf16x8*)&sB[srow + 64][sslot * 8] = rb1;
        __syncthreads();
        if (ks < 15) {
            int k0 = (ks + 1) * 32;
            ra0 = *(const bf16x8*)(Ap + k0);
            ra1 = *(const bf16x8*)(Ap + (size_t)64 * 512 + k0);
            rb0 = *(const bf16x8*)(Wp + k0);
            rb1 = *(const bf16x8*)(Wp + (size_t)64 * 512 + k0);
        }
        bf16x8 af[4], bfr[4];
        #pragma unroll
        for (int m = 0; m < 4; m++)
            af[m] = *(const bf16x8*)&sA[wr * 64 + m * 16 + c][g * 8];
        #pragma unroll
        for (int n = 0; n < 4; n++)
            bfr[n] = *(const bf16x8*)&sB[wc * 64 + n * 16 + c][g * 8];
        #pragma unroll
        for (int m = 0; m < 4; m++)
            #pragma unroll
            for (int n = 0; n < 4; n++)
                acc[m][n] = MFMA16(af[m], bfr[n], acc[m][n]);
    }

    #pragma unroll
    for (int m = 0; m < 4; m++) {
        int rbase = m0 + wr * 64 + m * 16 + 4 * g;
        #pragma unroll
        for (int n = 0; n < 4; n++) {
            int f = n0 + wc * 64 + n * 16 + c;
            f32x4 v = acc[m][n];
            float bv = bias[f];
            if (MODE == 1) {
                #pragma unroll
                for (int reg = 0; reg < 4; reg++)
                    Dout[(size_t)(rbase + reg) * E_ + f] = v[reg] + bv;
            } else {
                int part = f >> 9, w = f & 511, h = w >> 6, d = w & 63;
                int bb = rbase >> 10;
                int l0 = rbase & 1023;
                size_t bh = (size_t)(bb * H_ + h);
                if (part == 0) {
                    float qs = qscale[d];
                    #pragma unroll
                    for (int reg = 0; reg < 4; reg++)
                        Qb[(bh * L_ + l0 + reg) * DH + d] = f2b((v[reg] + bv) * qs);
                } else if (part == 1) {
                    #pragma unroll
                    for (int reg = 0; reg < 4; reg++)
                        Kb[(bh * L_ + l0 + reg) * DH + d] = f2b(v[reg] + bv);
                } else {
                    ushort4 pk;
                    pk.x = f2b(v[0] + bv); pk.y = f2b(v[1] + bv);
                    pk.z = f2b(v[2] + bv); pk.w = f2b(v[3] + bv);
                    *(ushort4*)(Vtb + (bh * DH + d) * L_ + l0) = pk;
                }
            }
        }
    }
}

// ---------------- MFMA flash attention, 32x32x16 (QB=32 per wave) ----------
// Block = 4 waves, SAME bh, 4 consecutive 32-row Q tiles (128 q-rows/block,
// 8 blocks per bh, grid 1024). Per 32-key tile: block stages K (32x64, 4KB) +
// V^T (64x32, 4KB) into double-buffered LDS via global_load_lds(16B); each
// wave drains its own DMA (vmcnt(0)) before the barrier (round-9 race fix).
// Swizzles identical to round 10 (LDS linear dest, inverse-XOR global src,
// XOR on read).  Swapped QK^T via mfma_32x32x16: S^T[key=row][q=col=lane&31];
// softmax state col-space (q=lane&31, xor32-reduced so both hi-halves agree);
// oacc row-space (q=(reg&3)+8*(reg>>2)+4*hi) -> rescale remaps via shfl.
// VALU diet vs round 10: hardware v_cvt_pk_bf16_f32 for P-pack, raw exp2,
// 2x work per wave amortizing all per-tile fixed costs.
__global__ __launch_bounds__(256, 4) void attn_mfma(
    const u16* __restrict__ Q, const u16* __restrict__ K,
    const u16* __restrict__ Vt, const unsigned char* __restrict__ mask,
    u16* __restrict__ O)
{
    __shared__ u16 Kbuf[2][2048];              // 2 x 4KB (256 slots x 16B)
    __shared__ u16 Vbuf[2][2048];              // 2 x 4KB
    __shared__ u16 P_lds[4][32][36];           // per-wave 32x32 P + pad

    const int bid = blockIdx.x;                // 0..1023
    const int w = (bid & 7) * 128 + (bid >> 3);  // XCD-bijective swizzle
    const int bh = w >> 3;                     // 0..127
    const int blk = w & 7;                     // 0..7 within bh
    const int tid = threadIdx.x;
    const int wid = tid >> 6;
    const int q0 = blk * 128 + wid * 32;       // wave's q base
    const int b = bh >> 3;
    const int h = bh & (H_ - 1);

    const int lane = tid & 63;
    const int c = lane & 31;                   // MFMA32 column
    const int hi = lane >> 5;

    const u16* Qp = Q + ((size_t)bh * L_ + q0) * DH;
    const u16* Kp = K + (size_t)bh * L_ * DH;
    const u16* Vp = Vt + (size_t)bh * DH * L_;
    const unsigned char* mp = mask + (size_t)b * L_;

    // staging map (identical to round 10): thread covers slot tid
    const int krow = tid >> 3, kch = (tid & 7) ^ (krow & 7);
    const int vrow = tid >> 2, vch = (tid & 3) ^ ((vrow & 3) ^ ((vrow >> 2) & 3));
    const u16* Kg = Kp + (size_t)krow * DH + kch * 8;   // + kt*DH per tile
    const u16* Vg = Vp + (size_t)vrow * L_ + vch * 8;   // + kt per tile

    auto stage = [&](int nbuf, int kt) {
        __builtin_amdgcn_global_load_lds(
            (const __attribute__((address_space(1))) unsigned int*)(Kg + (size_t)kt * DH),
            (__attribute__((address_space(3))) unsigned int*)&Kbuf[nbuf][wid * 512],
            16, 0, 0);
        __builtin_amdgcn_global_load_lds(
            (const __attribute__((address_space(1))) unsigned int*)(Vg + kt),
            (__attribute__((address_space(3))) unsigned int*)&Vbuf[nbuf][wid * 512],
            16, 0, 0);
    };

    // whole-row mask presence check (hoisted; mask is usually all-false)
    unsigned int mor = 0;
    {
        const unsigned int* mp32 = (const unsigned int*)mp;
        #pragma unroll
        for (int i = 0; i < 4; i++) mor |= mp32[lane + i * 64];
    }
    const bool anyMask = (__ballot(mor != 0) != 0ULL);

    stage(0, 0);                               // prefetch tile 0

    // Q B-fragments: B[k=d][col=q=c] = Q[c][d], d = s2*16 + hi*8 + j
    bf16x8 qf[4];
    #pragma unroll
    for (int s2 = 0; s2 < 4; s2++)
        qf[s2] = *(const bf16x8*)(Qp + c * DH + s2 * 16 + hi * 8);

    f32x16 oacc0 = {}, oacc1 = {};
    float mrun = -INFINITY, lrun = 0.f;

    // read-side swizzled LDS offsets (u16 indices)
    // K A-frag (s2): row=key=c, d-chunk (2*s2+hi): slot = c*8 + ((2s2+hi)^(c&7))
    int kslot[4];
    #pragma unroll
    for (int s2 = 0; s2 < 4; s2++)
        kslot[s2] = (c * 8 + (((2 * s2 + hi)) ^ (c & 7))) * 8;
    // V B-frag (dt,s): row=d=dt*32+c, key-chunk (2s+hi): slot = d*4 + ((2s+hi)^swzv)
    const int swzv = (c & 3) ^ ((c >> 2) & 3);
    int vslot[2][2];
    #pragma unroll
    for (int dt = 0; dt < 2; dt++)
        #pragma unroll
        for (int s = 0; s < 2; s++)
            vslot[dt][s] = ((dt * 32 + c) * 4 + (((2 * s + hi)) ^ swzv)) * 8;

    #pragma unroll 1
    for (int t = 0; t < 32; ++t) {
        const int cur = t & 1;
        const int kt = t * 32;
        // retire this wave's own staging DMA before the barrier (race fix)
        asm volatile("s_waitcnt vmcnt(0) lgkmcnt(0)" ::: "memory");
        __syncthreads();

        bf16x8 kf[4];
        #pragma unroll
        for (int s2 = 0; s2 < 4; s2++)
            kf[s2] = *(const bf16x8*)&Kbuf[cur][kslot[s2]];
        bf16x8 vf[2][2];
        #pragma unroll
        for (int dt = 0; dt < 2; dt++)
            #pragma unroll
            for (int s = 0; s < 2; s++)
                vf[dt][s] = *(const bf16x8*)&Vbuf[cur][vslot[dt][s]];

        if (t < 31) stage(cur ^ 1, kt + 32);   // prefetch next tile

        // S^T = K @ Q^T : lane holds S^T[key=(r&3)+8*(r>>2)+4*hi][q=c]
        f32x16 st = {};
        #pragma unroll
        for (int s2 = 0; s2 < 4; s2++)
            st = MFMA32(kf[s2], qf[s2], st);

        if (anyMask) {
            #pragma unroll
            for (int r = 0; r < 16; r++) {
                int key = kt + (r & 3) + 8 * (r >> 2) + 4 * hi;
                if (mp[key]) st[r] = -1e9f;
            }
        }

        // tile max (balanced tree) + cross-half combine
        float m01 = fmaxf(st[0], st[1]),  m23 = fmaxf(st[2], st[3]);
        float m45 = fmaxf(st[4], st[5]),  m67 = fmaxf(st[6], st[7]);
        float m89 = fmaxf(st[8], st[9]),  mab = fmaxf(st[10], st[11]);
        float mcd = fmaxf(st[12], st[13]), mef = fmaxf(st[14], st[15]);
        float tm = fmaxf(fmaxf(fmaxf(m01, m23), fmaxf(m45, m67)),
                         fmaxf(fmaxf(m89, mab), fmaxf(mcd, mef)));
        tm = fmaxf(tm, __shfl_xor(tm, 32));

        if (!__all(tm <= mrun + 8.f)) {        // defer-max rescale (rare)
            float mnew = fmaxf(mrun, tm);
            float corr = EXP2(mrun - mnew);    // col space (q=c)
            lrun *= corr;
            #pragma unroll
            for (int r = 0; r < 16; r++) {
                int row = (r & 3) + 8 * (r >> 2) + 4 * hi;
                float cr = __shfl(corr, row);
                oacc0[r] *= cr;
                oacc1[r] *= cr;
            }
            mrun = mnew;
        }

        // p = exp2(st - mrun); sum in col space (balanced tree)
        float p[16];
        #pragma unroll
        for (int r = 0; r < 16; r++) p[r] = EXP2(st[r] - mrun);
        float s01 = (p[0] + p[1]) + (p[2] + p[3]);
        float s23 = (p[4] + p[5]) + (p[6] + p[7]);
        float s45 = (p[8] + p[9]) + (p[10] + p[11]);
        float s67 = (p[12] + p[13]) + (p[14] + p[15]);
        float ls = (s01 + s23) + (s45 + s67);
        ls += __shfl_xor(ls, 32);
        lrun += ls;

        // P^T -> per-wave LDS [q][key] via hw packed cvt; reg r' covers keys
        // 8r'+4hi..+3 of row q=c.
        #pragma unroll
        for (int rp = 0; rp < 4; rp++) {
            uint2 pw;
            pw.x = cvt_pk_bf16(p[4 * rp], p[4 * rp + 1]);
            pw.y = cvt_pk_bf16(p[4 * rp + 2], p[4 * rp + 3]);
            *(uint2*)(&P_lds[wid][c][8 * rp + 4 * hi]) = pw;
        }
        asm volatile("s_waitcnt lgkmcnt(0)" ::: "memory");
        __builtin_amdgcn_sched_barrier(0);
        // PV A-frags: A[row=q=c][key = s*16 + hi*8 + j]
        bf16x8 pa0 = *(const bf16x8*)(&P_lds[wid][c][hi * 8]);
        bf16x8 pa1 = *(const bf16x8*)(&P_lds[wid][c][16 + hi * 8]);
        asm volatile("" ::: "memory");

        oacc0 = MFMA32(pa0, vf[0][0], oacc0);
        oacc0 = MFMA32(pa1, vf[0][1], oacc0);
        oacc1 = MFMA32(pa0, vf[1][0], oacc1);
        oacc1 = MFMA32(pa1, vf[1][1], oacc1);
        // oacc: lane holds O[q=(r&3)+8*(r>>2)+4*hi][d = dt*32 + c]
    }

    #pragma unroll
    for (int r = 0; r < 16; r++) {
        int row = (r & 3) + 8 * (r >> 2) + 4 * hi;
        float lq = __shfl(lrun, row);
        float inv = 1.f / lq;
        size_t base = ((size_t)(b * L_ + q0 + row)) * E_ + h * DH + c;
        O[base] = f2b(oacc0[r] * inv);
        O[base + 32] = f2b(oacc1[r] * inv);
    }
}

// ---------------- host launch ----------------
extern "C" void kernel_launch(void* const* d_in, const int* in_sizes, int n_in,
                              void* d_out, int out_size, void* d_ws, size_t ws_size,
                              hipStream_t stream) {
    const float* x     = (const float*)d_in[0];
    const float* w_in  = (const float*)d_in[1];
    const float* b_in  = (const float*)d_in[2];
    const float* w_out = (const float*)d_in[3];
    const float* b_out = (const float*)d_in[4];
    const float* qs    = (const float*)d_in[5];
    const unsigned char* mask = (const unsigned char*)d_in[6];
    float* out = (float*)d_out;

    char* base = (char*)d_ws;
    const size_t NELEM = (size_t)B_ * L_ * E_;   // 8388608
    float* qscale = (float*)base;                // 256 B
    u16* xb  = (u16*)(base + 256);
    u16* wib = xb + NELEM;                       // 786432
    u16* wob = wib + 786432;                     // 262144
    u16* Qb  = wob + 262144;
    u16* Kb  = Qb + NELEM;
    u16* Vtb = Kb + NELEM;
    u16* Ob  = Vtb + NELEM;

    qscale_kernel<<<1, 64, 0, stream>>>(qs, qscale);
    cvt_bf16<<<4608, 256, 0, stream>>>(x, w_in, w_out, xb, wib, wob);
    gemm_bf16<0><<<dim3(128, 12), 256, 0, stream>>>(
        xb, wib, b_in, qscale, nullptr, Qb, Kb, Vtb);
    attn_mfma<<<dim3(1024), 256, 0, stream>>>(Qb, Kb, Vtb, mask, Ob);
    gemm_bf16<1><<<dim3(128, 4), 256, 0, stream>>>(
        Ob, wob, b_out, nullptr, out, nullptr, nullptr, nullptr);
}